// Round 3
// baseline (646.703 us; speedup 1.0000x reference)
//
#include <hip/hip_runtime.h>

#define N_NODES   1000000
#define N_EDGES   2000000
#define N_FEAT    11
#define HIDDEN    64
#define BATCH     128
#define N_CLASSES 19

#define NPB       1024                            // nodes per bucket (pow2 -> bucket = col>>10)
#define NBUCK     ((N_NODES + NPB - 1) / NPB)     // 977
#define EPB       8192                            // edges per partition block
#define PBLK      ((N_EDGES + EPB - 1) / EPB)     // 245
#define NSLOT     8                               // pool slots per bucket (batch sorted -> ~2 used)

// ---- K1: per-block LDS histogram of targets by bucket -> global bucket counts
__global__ __launch_bounds__(256) void hist_kernel(const int* __restrict__ col,
                                                   int* __restrict__ bcnt) {
    __shared__ int lh[NPB];
    for (int i = threadIdx.x; i < NPB; i += 256) lh[i] = 0;
    __syncthreads();
    const int base = blockIdx.x * EPB;
#pragma unroll
    for (int i = 0; i < EPB / 256; ++i) {
        int e = base + i * 256 + threadIdx.x;
        if (e < N_EDGES) atomicAdd(&lh[col[e] >> 10], 1);
    }
    __syncthreads();
    for (int b = threadIdx.x; b < NBUCK; b += 256) {
        int v = lh[b];
        if (v) atomicAdd(&bcnt[b], v);   // ~250k global atomics total
    }
}

// ---- K2: exclusive scan of 977 bucket counts (single block) ----
__global__ __launch_bounds__(1024) void scan_kernel(const int* __restrict__ bcnt,
                                                    int* __restrict__ bstart,
                                                    int* __restrict__ cursor) {
    __shared__ int sh[1024];
    const int t = threadIdx.x;
    int v = (t < NBUCK) ? bcnt[t] : 0;
    sh[t] = v;
    __syncthreads();
    for (int off = 1; off < 1024; off <<= 1) {
        int a = (t >= off) ? sh[t - off] : 0;
        __syncthreads();
        sh[t] += a;
        __syncthreads();
    }
    if (t < NBUCK) { int ex = sh[t] - v; bstart[t] = ex; cursor[t] = ex; }
}

// ---- K3: multisplit scatter — one global atomic per (block,bucket), payload 4B packed
__global__ __launch_bounds__(256) void part_kernel(const int* __restrict__ row,
                                                   const int* __restrict__ col,
                                                   int* __restrict__ cursor,
                                                   unsigned* __restrict__ part) {
    __shared__ int lh[NPB];
    const int t = threadIdx.x;
    for (int i = t; i < NPB; i += 256) lh[i] = 0;
    __syncthreads();
    const int base = blockIdx.x * EPB;
#pragma unroll
    for (int i = 0; i < EPB / 256; ++i) {
        int e = base + i * 256 + t;
        if (e < N_EDGES) atomicAdd(&lh[col[e] >> 10], 1);
    }
    __syncthreads();
    for (int b = t; b < NBUCK; b += 256) {
        int v = lh[b];
        lh[b] = v ? atomicAdd(&cursor[b], v) : 0;   // lh now holds running write pos
    }
    __syncthreads();
#pragma unroll
    for (int i = 0; i < EPB / 256; ++i) {
        int e = base + i * 256 + t;
        if (e < N_EDGES) {
            int c = col[e];
            int pos = atomicAdd(&lh[c >> 10], 1);   // LDS atomic rank
            part[pos] = ((unsigned)row[e] << 10) | (unsigned)(c & (NPB - 1));
        }
    }
}

// ---- K4: per-bucket degree histogram in LDS -> dinv (no global atomics) ----
__global__ __launch_bounds__(256) void deg_dinv_kernel(const unsigned* __restrict__ part,
                                                       const int* __restrict__ bstart,
                                                       const int* __restrict__ bcnt,
                                                       float* __restrict__ dinv) {
    __shared__ int ideg[NPB];
    const int t = threadIdx.x, b = blockIdx.x;
    for (int i = t; i < NPB; i += 256) ideg[i] = 0;
    __syncthreads();
    const int s0 = bstart[b], e0 = s0 + bcnt[b];
    for (int j = s0 + t; j < e0; j += 256)
        atomicAdd(&ideg[part[j] & (NPB - 1)], 1);
    __syncthreads();
    for (int i = t; i < NPB; i += 256) {
        int n = b * NPB + i;
        if (n < N_NODES) {
            int d = ideg[i];
            dinv[n] = d ? rsqrtf((float)d) : 0.0f;
        }
    }
}

// ---- K5: per-bucket LDS aggregation + fused transform/relu/mean-pool ----
__global__ __launch_bounds__(256) void agg_pool_kernel(
    const unsigned* __restrict__ part, const int* __restrict__ bstart,
    const int* __restrict__ bcnt, const float* __restrict__ x,
    const float* __restrict__ dinv, const int* __restrict__ batch,
    const float* __restrict__ Wc, const float* __restrict__ bc,
    float* __restrict__ pooled, float* __restrict__ countsf) {
    __shared__ float facc[NPB * N_FEAT];     // 44 KB
    __shared__ float pbuf[NSLOT * HIDDEN];   // 2 KB
    __shared__ int   pcnt[NSLOT];
    const int t = threadIdx.x, b = blockIdx.x;
    for (int i = t; i < NPB * N_FEAT; i += 256) facc[i] = 0.0f;
    for (int i = t; i < NSLOT * HIDDEN; i += 256) pbuf[i] = 0.0f;
    if (t < NSLOT) pcnt[t] = 0;
    __syncthreads();

    // edge phase: facc[cl,:] += dinv[row] * x[row,:]
    const int s0 = bstart[b], e0 = s0 + bcnt[b];
    for (int j = s0 + t; j < e0; j += 256) {
        unsigned p = part[j];
        int row = (int)(p >> 10);
        int cl  = (int)(p & (NPB - 1));
        float nr = dinv[row];
        if (nr != 0.0f) {
            const float* xr = x + (size_t)row * N_FEAT;
#pragma unroll
            for (int k = 0; k < N_FEAT; ++k)
                atomicAdd(&facc[cl * N_FEAT + k], nr * xr[k]);
        }
    }
    __syncthreads();

    // transform + pool: lane owns hidden channel, wave w owns nodes [w*256, w*256+256)
    const int lane = t & 63;
    const int w    = t >> 6;
    float wk[N_FEAT];
#pragma unroll
    for (int k = 0; k < N_FEAT; ++k) wk[k] = Wc[k * HIDDEN + lane];
    const float bias = bc[lane];
    const int lo = b * NPB;
    const int bid0 = batch[lo];
    for (int i = w * 256; i < w * 256 + 256; ++i) {
        int n = lo + i;
        if (n >= N_NODES) break;
        int bid  = batch[n];   // same addr across lanes -> one line
        float dc = dinv[n];
        float s = 0.0f;
#pragma unroll
        for (int k = 0; k < N_FEAT; ++k) s = fmaf(wk[k], facc[i * N_FEAT + k], s);  // LDS broadcast
        float h = fmaxf(fmaf(dc, s, bias), 0.0f);
        int slot = bid - bid0;   // batch sorted: ~0..1 within a 1024-node bucket
        if (slot < NSLOT) {
            atomicAdd(&pbuf[slot * HIDDEN + lane], h);
            if (lane == 0) atomicAdd(&pcnt[slot], 1);
        } else {  // safety fallback, ~never taken
            atomicAdd(&pooled[(size_t)bid * HIDDEN + lane], h);
            if (lane == 0) atomicAdd(&countsf[bid], 1.0f);
        }
    }
    __syncthreads();
    for (int s = w; s < NSLOT; s += 4) {
        int c = pcnt[s];
        if (c) {
            atomicAdd(&pooled[(size_t)(bid0 + s) * HIDDEN + lane], pbuf[s * HIDDEN + lane]);
            if (lane == 0) atomicAdd(&countsf[bid0 + s], (float)c);
        }
    }
}

// ---- K6: out = (pooled/cnt) @ W_lin + b_lin ----
__global__ void final_kernel(const float* __restrict__ pooled, const float* __restrict__ counts,
                             const float* __restrict__ Wl, const float* __restrict__ bl,
                             float* __restrict__ out) {
    int i = blockIdx.x * blockDim.x + threadIdx.x;
    if (i >= BATCH * N_CLASSES) return;
    int b = i / N_CLASSES;
    int c = i - b * N_CLASSES;
    float inv = 1.0f / fmaxf(counts[b], 1.0f);
    float s = bl[c];
#pragma unroll 8
    for (int h = 0; h < HIDDEN; ++h)
        s = fmaf(pooled[b * HIDDEN + h] * inv, Wl[h * N_CLASSES + c], s);
    out[i] = s;
}

extern "C" void kernel_launch(void* const* d_in, const int* in_sizes, int n_in,
                              void* d_out, int out_size, void* d_ws, size_t ws_size,
                              hipStream_t stream) {
    // inputs: x, edge_index, y(unused), batch, W_conv, b_conv, W_lin, b_lin
    const float* x     = (const float*)d_in[0];
    const int*   ei    = (const int*)d_in[1];   // [2, E] int32
    const int*   batch = (const int*)d_in[3];
    const float* Wc    = (const float*)d_in[4];
    const float* bc    = (const float*)d_in[5];
    const float* Wl    = (const float*)d_in[6];
    const float* bl    = (const float*)d_in[7];
    float*       out   = (float*)d_out;

    // ws: [bcnt NPB][pooled 8192f][countsf 128f] (zeroed) | bstart | cursor | dinv | part
    int*      bcnt    = (int*)d_ws;
    float*    pooled  = (float*)(bcnt + NPB);
    float*    countsf = pooled + BATCH * HIDDEN;
    int*      bstart  = (int*)(countsf + BATCH);
    int*      cursor  = bstart + NPB;
    float*    dinv    = (float*)(cursor + NPB);
    unsigned* part    = (unsigned*)(dinv + N_NODES);

    size_t zero_bytes = ((size_t)NPB + BATCH * HIDDEN + BATCH) * 4;  // ~37 KB
    hipMemsetAsync(d_ws, 0, zero_bytes, stream);

    const int* row = ei;
    const int* col = ei + N_EDGES;

    hist_kernel    <<<PBLK, 256, 0, stream>>>(col, bcnt);
    scan_kernel    <<<1, 1024, 0, stream>>>(bcnt, bstart, cursor);
    part_kernel    <<<PBLK, 256, 0, stream>>>(row, col, cursor, part);
    deg_dinv_kernel<<<NBUCK, 256, 0, stream>>>(part, bstart, bcnt, dinv);
    agg_pool_kernel<<<NBUCK, 256, 0, stream>>>(part, bstart, bcnt, x, dinv, batch,
                                               Wc, bc, pooled, countsf);
    final_kernel   <<<(BATCH * N_CLASSES + 255) / 256, 256, 0, stream>>>(pooled, countsf, Wl, bl, out);
}

// Round 4
// 291.417 us; speedup vs baseline: 2.2192x; 2.2192x over previous
//
#include <hip/hip_runtime.h>

#define N_NODES   1000000
#define N_EDGES   2000000
#define N_FEAT    11
#define HIDDEN    64
#define BATCH     128
#define N_CLASSES 19

#define NPB       1024                            // nodes per bucket (bucket = col>>10)
#define NBUCK     ((N_NODES + NPB - 1) / NPB)     // 977
#define EPB       8192                            // edges per partition block
#define PBLK      ((N_EDGES + EPB - 1) / EPB)     // 245
#define NSLOT     8                               // pool slots per block span
#define GPB       2048                            // gather_pool blocks

// ---- K1: per-block LDS histogram of targets by bucket -> global bucket counts
__global__ __launch_bounds__(256) void hist_kernel(const int* __restrict__ col,
                                                   int* __restrict__ bcnt) {
    __shared__ int lh[NPB];
    for (int i = threadIdx.x; i < NPB; i += 256) lh[i] = 0;
    __syncthreads();
    const int base = blockIdx.x * EPB;
#pragma unroll
    for (int i = 0; i < EPB / 256; ++i) {
        int e = base + i * 256 + threadIdx.x;
        if (e < N_EDGES) atomicAdd(&lh[col[e] >> 10], 1);
    }
    __syncthreads();
    for (int b = threadIdx.x; b < NBUCK; b += 256) {
        int v = lh[b];
        if (v) atomicAdd(&bcnt[b], v);
    }
}

// ---- K2: exclusive scan of bucket counts; also seed nstart[N_NODES] ----
__global__ __launch_bounds__(1024) void scan_kernel(const int* __restrict__ bcnt,
                                                    int* __restrict__ bstart,
                                                    int* __restrict__ cursor,
                                                    int* __restrict__ nstart) {
    __shared__ int sh[1024];
    const int t = threadIdx.x;
    int v = (t < NBUCK) ? bcnt[t] : 0;
    sh[t] = v;
    __syncthreads();
    for (int off = 1; off < 1024; off <<= 1) {
        int a = (t >= off) ? sh[t - off] : 0;
        __syncthreads();
        sh[t] += a;
        __syncthreads();
    }
    if (t < NBUCK) { int ex = sh[t] - v; bstart[t] = ex; cursor[t] = ex; }
    if (t == 1023) nstart[N_NODES] = N_EDGES;
}

// ---- K3: multisplit scatter — one global atomic per (block,bucket) ----
__global__ __launch_bounds__(256) void part_kernel(const int* __restrict__ row,
                                                   const int* __restrict__ col,
                                                   int* __restrict__ cursor,
                                                   unsigned* __restrict__ part) {
    __shared__ int lh[NPB];
    const int t = threadIdx.x;
    for (int i = t; i < NPB; i += 256) lh[i] = 0;
    __syncthreads();
    const int base = blockIdx.x * EPB;
#pragma unroll
    for (int i = 0; i < EPB / 256; ++i) {
        int e = base + i * 256 + t;
        if (e < N_EDGES) atomicAdd(&lh[col[e] >> 10], 1);
    }
    __syncthreads();
    for (int b = t; b < NBUCK; b += 256) {
        int v = lh[b];
        lh[b] = v ? atomicAdd(&cursor[b], v) : 0;   // lh becomes running write pos
    }
    __syncthreads();
#pragma unroll
    for (int i = 0; i < EPB / 256; ++i) {
        int e = base + i * 256 + t;
        if (e < N_EDGES) {
            int c = col[e];
            int pos = atomicAdd(&lh[c >> 10], 1);   // LDS rank
            part[pos] = ((unsigned)row[e] << 10) | (unsigned)(c & (NPB - 1));
        }
    }
}

// ---- K4: per-bucket counting sort -> CSR (srcs, nstart) + dinv; no global atomics
__global__ __launch_bounds__(256) void sort2_kernel(const unsigned* __restrict__ part,
                                                    const int* __restrict__ bstart,
                                                    const int* __restrict__ bcnt,
                                                    int* __restrict__ srcs,
                                                    int* __restrict__ nstart,
                                                    float* __restrict__ dinv) {
    __shared__ int cnt[NPB];
    __shared__ int off[NPB];
    __shared__ int tsum[256];
    const int t = threadIdx.x, b = blockIdx.x;
    for (int i = t; i < NPB; i += 256) cnt[i] = 0;
    __syncthreads();
    const int s0 = bstart[b], e0 = s0 + bcnt[b];
    for (int j = s0 + t; j < e0; j += 256)
        atomicAdd(&cnt[part[j] & (NPB - 1)], 1);
    __syncthreads();
    // exclusive scan of 1024 counts: 4 per thread + Hillis-Steele over thread sums
    const int i0 = t * 4;
    int c0 = cnt[i0], c1 = cnt[i0 + 1], c2 = cnt[i0 + 2], c3 = cnt[i0 + 3];
    int s = c0 + c1 + c2 + c3;
    tsum[t] = s;
    __syncthreads();
    for (int o = 1; o < 256; o <<= 1) {
        int a = (t >= o) ? tsum[t - o] : 0;
        __syncthreads();
        tsum[t] += a;
        __syncthreads();
    }
    int ex = tsum[t] - s;
    off[i0] = ex; off[i0 + 1] = ex + c0; off[i0 + 2] = ex + c0 + c1; off[i0 + 3] = ex + c0 + c1 + c2;
#pragma unroll
    for (int q = 0; q < 4; ++q) {
        int i = i0 + q, n = b * NPB + i;
        if (n < N_NODES) {
            int d = cnt[i];
            dinv[n]   = d ? rsqrtf((float)d) : 0.0f;
            nstart[n] = s0 + off[i];
        }
    }
    __syncthreads();
    for (int j = s0 + t; j < e0; j += 256) {
        unsigned p = part[j];
        int cl = (int)(p & (NPB - 1));
        int pos = s0 + atomicAdd(&off[cl], 1);
        srcs[pos] = (int)(p >> 10);
    }
}

// ---- K5: xs[n,0..10] = dinv[n] * x[n,:], padded to 16 floats (64 B aligned) ----
__global__ __launch_bounds__(256) void xpad_kernel(const float* __restrict__ x,
                                                   const float* __restrict__ dinv,
                                                   float* __restrict__ xs) {
    int n = blockIdx.x * blockDim.x + threadIdx.x;
    if (n >= N_NODES) return;
    float d = dinv[n];
    const float* xr = x + (size_t)n * N_FEAT;
    float4 A, B, C;
    A.x = d * xr[0];  A.y = d * xr[1];  A.z = d * xr[2];  A.w = d * xr[3];
    B.x = d * xr[4];  B.y = d * xr[5];  B.z = d * xr[6];  B.w = d * xr[7];
    C.x = d * xr[8];  C.y = d * xr[9];  C.z = d * xr[10]; C.w = 0.0f;
    float4* o = (float4*)(xs + (size_t)n * 16);
    o[0] = A; o[1] = B; o[2] = C;
}

// ---- K6: fused register gather + transform/relu + hierarchical mean-pool ----
__global__ __launch_bounds__(256) void gather_pool_kernel(
    const int* __restrict__ nstart, const int* __restrict__ srcs,
    const float* __restrict__ xs, const float* __restrict__ dinv,
    const int* __restrict__ batch, const float* __restrict__ Wc,
    const float* __restrict__ bc, float* __restrict__ pooled,
    float* __restrict__ countsf) {
    __shared__ float facc[256 * N_FEAT];    // 11 KB
    __shared__ float pbuf[NSLOT * HIDDEN];  // 2 KB
    __shared__ int   pcnt[NSLOT];
    const int t = threadIdx.x, lane = t & 63, w = t >> 6;
    const long per = (N_NODES + GPB - 1) / GPB;       // contiguous span per block
    const long lo  = (long)blockIdx.x * per;
    const long hi  = (lo + per < N_NODES) ? lo + per : N_NODES;
    if (lo >= hi) return;  // uniform across block

    for (int i = t; i < NSLOT * HIDDEN; i += 256) pbuf[i] = 0.0f;
    if (t < NSLOT) pcnt[t] = 0;
    float wk[N_FEAT];
#pragma unroll
    for (int k = 0; k < N_FEAT; ++k) wk[k] = Wc[k * HIDDEN + lane];
    const float bias = bc[lane];
    const int bid0 = batch[lo];
    int cur = -1; float accp = 0.0f; int cntp = 0;
    __syncthreads();

    for (long cbase = lo; cbase < hi; cbase += 256) {
        // phase A: thread-per-node register gather
        long n = cbase + t;
        float acc[N_FEAT];
#pragma unroll
        for (int k = 0; k < N_FEAT; ++k) acc[k] = 0.0f;
        if (n < hi) {
            int j0 = nstart[n], j1 = nstart[n + 1];
            float dc = dinv[n];
            for (int j = j0; j < j1; ++j) {
                int r = srcs[j];
                const float4* xr = (const float4*)(xs + (size_t)r * 16);
                float4 A = xr[0], B = xr[1], C = xr[2];   // one 64B line
                acc[0] += A.x; acc[1] += A.y; acc[2]  += A.z; acc[3] += A.w;
                acc[4] += B.x; acc[5] += B.y; acc[6]  += B.z; acc[7] += B.w;
                acc[8] += C.x; acc[9] += C.y; acc[10] += C.z;
            }
#pragma unroll
            for (int k = 0; k < N_FEAT; ++k) acc[k] *= dc;
        }
#pragma unroll
        for (int k = 0; k < N_FEAT; ++k) facc[t * N_FEAT + k] = acc[k];
        __syncthreads();

        // phase B: wave w owns nodes [cbase+w*64, +64); lane owns hidden channel
        const long nb = cbase + (long)w * 64;
        for (int i = 0; i < 64; ++i) {
            long n2 = nb + i;
            if (n2 >= hi) break;
            int bid = batch[n2];          // wave-uniform broadcast load
            if (bid != cur) {
                if (cur >= 0) {
                    int slot = cur - bid0;
                    if (slot >= 0 && slot < NSLOT) {
                        atomicAdd(&pbuf[slot * HIDDEN + lane], accp);
                        if (lane == 0) atomicAdd(&pcnt[slot], cntp);
                    } else {
                        atomicAdd(&pooled[(size_t)cur * HIDDEN + lane], accp);
                        if (lane == 0) atomicAdd(&countsf[cur], (float)cntp);
                    }
                }
                cur = bid; accp = 0.0f; cntp = 0;
            }
            float s = 0.0f;
#pragma unroll
            for (int k = 0; k < N_FEAT; ++k)
                s = fmaf(wk[k], facc[(w * 64 + i) * N_FEAT + k], s);  // LDS broadcast
            accp += fmaxf(s + bias, 0.0f);
            ++cntp;
        }
        __syncthreads();  // protect facc before next chunk
    }
    // final per-wave flush
    if (cur >= 0) {
        int slot = cur - bid0;
        if (slot >= 0 && slot < NSLOT) {
            atomicAdd(&pbuf[slot * HIDDEN + lane], accp);
            if (lane == 0) atomicAdd(&pcnt[slot], cntp);
        } else {
            atomicAdd(&pooled[(size_t)cur * HIDDEN + lane], accp);
            if (lane == 0) atomicAdd(&countsf[cur], (float)cntp);
        }
    }
    __syncthreads();
    // block-level flush of LDS slots (~1-2 nonzero per block)
    for (int s = w; s < NSLOT; s += 4) {
        int c = pcnt[s];
        if (c > 0) {
            atomicAdd(&pooled[(size_t)(bid0 + s) * HIDDEN + lane], pbuf[s * HIDDEN + lane]);
            if (lane == 0) atomicAdd(&countsf[bid0 + s], (float)c);
        }
    }
}

// ---- K7: out = (pooled/cnt) @ W_lin + b_lin ----
__global__ void final_kernel(const float* __restrict__ pooled, const float* __restrict__ counts,
                             const float* __restrict__ Wl, const float* __restrict__ bl,
                             float* __restrict__ out) {
    int i = blockIdx.x * blockDim.x + threadIdx.x;
    if (i >= BATCH * N_CLASSES) return;
    int b = i / N_CLASSES;
    int c = i - b * N_CLASSES;
    float inv = 1.0f / fmaxf(counts[b], 1.0f);
    float s = bl[c];
#pragma unroll 8
    for (int h = 0; h < HIDDEN; ++h)
        s = fmaf(pooled[b * HIDDEN + h] * inv, Wl[h * N_CLASSES + c], s);
    out[i] = s;
}

extern "C" void kernel_launch(void* const* d_in, const int* in_sizes, int n_in,
                              void* d_out, int out_size, void* d_ws, size_t ws_size,
                              hipStream_t stream) {
    // inputs: x, edge_index, y(unused), batch, W_conv, b_conv, W_lin, b_lin
    const float* x     = (const float*)d_in[0];
    const int*   ei    = (const int*)d_in[1];   // [2, E] int32
    const int*   batch = (const int*)d_in[3];
    const float* Wc    = (const float*)d_in[4];
    const float* bc    = (const float*)d_in[5];
    const float* Wl    = (const float*)d_in[6];
    const float* bl    = (const float*)d_in[7];
    float*       out   = (float*)d_out;

    // ws layout: xs[16M f, 64B-aligned] | bcnt[1024] pooled[8192] countsf[128] (zeroed)
    //            | bstart[1024] cursor[1024] | dinv[1M f] | part[2M u] | srcs[2M] | nstart[1M+8]
    float*    xs      = (float*)d_ws;
    int*      bcnt    = (int*)(xs + (size_t)N_NODES * 16);
    float*    pooled  = (float*)(bcnt + 1024);
    float*    countsf = pooled + BATCH * HIDDEN;
    int*      bstart  = (int*)(countsf + BATCH);
    int*      cursor  = bstart + 1024;
    float*    dinv    = (float*)(cursor + 1024);
    unsigned* part    = (unsigned*)(dinv + N_NODES);
    int*      srcs    = (int*)(part + N_EDGES);
    int*      nstart  = srcs + N_EDGES;

    size_t zero_bytes = (1024 + BATCH * HIDDEN + BATCH) * 4;  // bcnt+pooled+countsf
    hipMemsetAsync(bcnt, 0, zero_bytes, stream);

    const int* row = ei;
    const int* col = ei + N_EDGES;

    hist_kernel <<<PBLK, 256, 0, stream>>>(col, bcnt);
    scan_kernel <<<1, 1024, 0, stream>>>(bcnt, bstart, cursor, nstart);
    part_kernel <<<PBLK, 256, 0, stream>>>(row, col, cursor, part);
    sort2_kernel<<<NBUCK, 256, 0, stream>>>(part, bstart, bcnt, srcs, nstart, dinv);
    xpad_kernel <<<(N_NODES + 255) / 256, 256, 0, stream>>>(x, dinv, xs);
    gather_pool_kernel<<<GPB, 256, 0, stream>>>(nstart, srcs, xs, dinv, batch,
                                                Wc, bc, pooled, countsf);
    final_kernel<<<(BATCH * N_CLASSES + 255) / 256, 256, 0, stream>>>(pooled, countsf, Wl, bl, out);
}